// Round 3
// baseline (12.611 us; speedup 1.0000x reference)
//
#include <hip/hip_runtime.h>
#include <math.h>

// QuantumPerceptron: 5 qubits (DIM=32), 4 layers, 9 time steps.
// M = diag(D) + omega*X_(qubit4) -> 16 independent 2x2 blocks; exp(-i t M)
// closed form, hoisted (layer-invariant). U = tensor product of 5 single-qubit
// gates; adjacent gate pairs fused into 4x4 two-qubit hops (3 independent
// exchanges issued in parallel). H merged into U1's last gate (same pair mask).
// Chain: 6 hops/layer x 4 layers + 5 reduce hops = 29 cross-lane hops.

struct C2 { float x, y; };
__device__ __forceinline__ C2 cmul(C2 a, C2 b){ return {a.x*b.x - a.y*b.y, a.x*b.y + a.y*b.x}; }
__device__ __forceinline__ C2 cadd(C2 a, C2 b){ return {a.x+b.x, a.y+b.y}; }

// Cross-lane XOR exchange: DPP quad_perm for masks 1,2,3 (VALU latency),
// ds_swizzle BitMode otherwise. All masks <32 -> stay within a 32-lane group.
template<int MASK>
__device__ __forceinline__ float xl(float v){
    int i = __builtin_bit_cast(int, v), r;
    if constexpr (MASK == 1)      r = __builtin_amdgcn_mov_dpp(i, 0xB1, 0xF, 0xF, true); // [1,0,3,2]
    else if constexpr (MASK == 2) r = __builtin_amdgcn_mov_dpp(i, 0x4E, 0xF, 0xF, true); // [2,3,0,1]
    else if constexpr (MASK == 3) r = __builtin_amdgcn_mov_dpp(i, 0x1B, 0xF, 0xF, true); // [3,2,1,0]
    else                          r = __builtin_amdgcn_ds_swizzle(i, (MASK << 10) | 0x1F);
    return __builtin_bit_cast(float, r);
}
template<int MASK>
__device__ __forceinline__ C2 xl2(C2 v){ return { xl<MASK>(v.x), xl<MASK>(v.y) }; }

// Single-gate hop (2x2 on one bit).
template<int MASK>
__device__ __forceinline__ C2 pair_op(C2 amp, C2 dg, C2 of){
    C2 p = xl2<MASK>(amp);
    return cadd(cmul(dg, amp), cmul(of, p));
}

// Fused two-gate hop: amp' = (GA ⊗ GB) amp, GA on bit MA, GB on bit MB.
template<int MA, int MB>
__device__ __forceinline__ C2 pair2(C2 amp, C2 dgA, C2 ofA, C2 dgB, C2 ofB){
    const C2 aB  = xl2<MB>(amp);          // three independent exchanges:
    const C2 aA  = xl2<MA>(amp);          // one shuffle latency, not two
    const C2 aAB = xl2<MA ^ MB>(amp);
    const C2 c00 = cmul(dgA, dgB);        // amp-independent, hoistable
    const C2 c0B = cmul(dgA, ofB);
    const C2 cA0 = cmul(ofA, dgB);
    const C2 cAB = cmul(ofA, ofB);
    return cadd(cadd(cmul(c00, amp), cmul(c0B, aB)),
                cadd(cmul(cA0, aA), cmul(cAB, aAB)));
}

// G = e^{-igZ} e^{-ibX} e^{-iaZ}; row selected by `hi`.
// G00 = cb e^{-i(a+g)}, G11 = conj(G00); G01 = -i sb e^{+i(a-g)}, G10 = -conj(G01).
__device__ __forceinline__ void gc(const float* __restrict__ params, int idx, bool hi,
                                   C2& dg, C2& of){
    const float a = params[idx], b = params[40 + idx], g = params[80 + idx];
    const float spg = __sinf(a + g), cpg = __cosf(a + g);
    const float samg = __sinf(a - g), camg = __cosf(a - g);
    const float sb = __sinf(b), cb = __cosf(b);
    dg = { cb * cpg, hi ?  cb * spg : -cb * spg };
    of = { hi ? -sb * samg : sb * samg, -sb * camg };
}

__global__ __launch_bounds__(320)
void qp_kernel(const float* __restrict__ state,   // 16 f32
               const float* __restrict__ params,  // (3,4,2,5) = 120 f32
               const float* __restrict__ W,       // (2,9) f32
               const float* __restrict__ bias,    // (2,) f32
               float* __restrict__ out)           // (1,2) f32
{
    __shared__ float r_lds[9];

    const int tid    = threadIdx.x;
    const int lane32 = tid & 31;   // amplitude index
    const int tstep  = tid >> 5;   // 0..8 valid, 9 = idle tail
    const float t    = 0.1f * (float)(tstep + 1);

    // Prefetch tail operands NOW so their global latency hides under the chain.
    float wreg[9]; float breg = 0.f;
    if (tid < 2) {
        breg = bias[tid];
        #pragma unroll
        for (int q = 0; q < 9; ++q) wreg[q] = W[tid * 9 + q];
    }

    // psi = kron(state, [1,0])
    const int b0 = lane32 & 1;
    C2 amp = { b0 ? 0.f : state[lane32 >> 1], 0.f };

    // ---- H(t) 2x2 on pair (j, j^1), hoisted: layer-invariant ----
    const float fm  = (float)__popc(lane32 >> 1);
    const float hds = (b0 ? 1.f : -1.f) * (2.f * fm - 4.f);  // signed half-detuning
    const float Om  = sqrtf(hds * hds + 400.f);              // omega = -20
    const float sth = __sinf(Om * t), cth = __cosf(Om * t);
    const float k   = sth / Om;
    const float s4  = __sinf(4.f * t), c4 = __cosf(4.f * t);
    const C2 ph  = { c4, s4 };                               // e^{-ict}, c = -4
    const C2 hdg = cmul(ph, C2{ cth, -k * hds });
    const C2 hof = cmul(ph, C2{ 0.f, 20.f * k });            // -i k w, w = -20

    #pragma unroll
    for (int l = 0; l < 4; ++l) {
        const int bA = l * 10, bB = bA + 5;
        {   // U1 gates 0,1 (masks 16,8) fused
            C2 dgA, ofA, dgB, ofB;
            gc(params, bA + 0, (lane32 & 16) != 0, dgA, ofA);
            gc(params, bA + 1, (lane32 &  8) != 0, dgB, ofB);
            amp = pair2<16, 8>(amp, dgA, ofA, dgB, ofB);
        }
        {   // U1 gates 2,3 (masks 4,2) fused
            C2 dgA, ofA, dgB, ofB;
            gc(params, bA + 2, (lane32 & 4) != 0, dgA, ofA);
            gc(params, bA + 3, (lane32 & 2) != 0, dgB, ofB);
            amp = pair2<4, 2>(amp, dgA, ofA, dgB, ofB);
        }
        {   // K = H * G4 (both mask 1): one hop
            C2 dg, of; gc(params, bA + 4, b0 != 0, dg, of);
            const C2 ndg = cadd(cmul(hdg, dg), cmul(hof, C2{ -of.x,  of.y })); // hof * (-conj(of))
            const C2 nof = cadd(cmul(hdg, of), cmul(hof, C2{  dg.x, -dg.y })); // hof * conj(dg)
            amp = pair_op<1>(amp, ndg, nof);
        }
        {   // U2 gates 0,1 (masks 16,8) fused
            C2 dgA, ofA, dgB, ofB;
            gc(params, bB + 0, (lane32 & 16) != 0, dgA, ofA);
            gc(params, bB + 1, (lane32 &  8) != 0, dgB, ofB);
            amp = pair2<16, 8>(amp, dgA, ofA, dgB, ofB);
        }
        {   // U2 gates 2,3 (masks 4,2) fused
            C2 dgA, ofA, dgB, ofB;
            gc(params, bB + 2, (lane32 & 4) != 0, dgA, ofA);
            gc(params, bB + 3, (lane32 & 2) != 0, dgB, ofB);
            amp = pair2<4, 2>(amp, dgA, ofA, dgB, ofB);
        }
        {   // U2 gate 4 (mask 1)
            C2 dg, of; gc(params, bB + 4, b0 != 0, dg, of);
            amp = pair_op<1>(amp, dg, of);
        }
    }

    // r[t] = sum_even |amp|^2 - sum_odd |amp|^2 within each 32-lane group
    const float p = amp.x * amp.x + amp.y * amp.y;
    float sp = b0 ? -p : p;
    sp += xl<16>(sp);
    sp += xl<8>(sp);
    sp += xl<4>(sp);
    sp += xl<2>(sp);
    sp += xl<1>(sp);
    if (lane32 == 0 && tstep < 9) r_lds[tstep] = sp;
    __syncthreads();

    // out[o] = tanh(sum_t r[t] * W[o,t] + bias[o])  -- W/bias already in regs
    if (tid < 2) {
        float acc = breg;
        #pragma unroll
        for (int q = 0; q < 9; ++q) acc += r_lds[q] * wreg[q];
        out[tid] = tanhf(acc);
    }
}

extern "C" void kernel_launch(void* const* d_in, const int* in_sizes, int n_in,
                              void* d_out, int out_size, void* d_ws, size_t ws_size,
                              hipStream_t stream) {
    const float* state  = (const float*)d_in[0];
    const float* params = (const float*)d_in[1];
    const float* W      = (const float*)d_in[2];
    const float* bias   = (const float*)d_in[3];
    float* out = (float*)d_out;
    qp_kernel<<<1, 320, 0, stream>>>(state, params, W, bias, out);
}

// Round 4
// 9.726 us; speedup vs baseline: 1.2967x; 1.2967x over previous
//
#include <hip/hip_runtime.h>
#include <math.h>

// QuantumPerceptron: 5 qubits (DIM=32), 4 layers, 9 time steps.
// Issue-bound single-block kernel (R3 post-mortem: fewer-but-fatter hops lost;
// minimize per-wave instruction count).
//   Phase 1: threads 0..39 build the 40-gate coefficient table (time- and
//            lane-independent up to signs) in LDS: 6 transcendentals TOTAL
//            per lane instead of ~250.
//   Phase 2: all lanes run the 45-hop chain; each gate = uniform ds_read_b128
//            (broadcast) + 2 sign-selects + 8 FMA + 2 cross-lane exchanges
//            (DPP for masks 1,2; ds_swizzle for 4,8,16).
// H(t) = exp(-i t M): M = diag + omega*X_q4 -> closed-form 2x2 per pair,
// per-lane coefficients hoisted out of the layer loop (layer-invariant).

struct C2 { float x, y; };
__device__ __forceinline__ C2 cmul(C2 a, C2 b){ return {a.x*b.x - a.y*b.y, a.x*b.y + a.y*b.x}; }
__device__ __forceinline__ C2 cadd(C2 a, C2 b){ return {a.x+b.x, a.y+b.y}; }

// Cross-lane XOR exchange within 32-lane groups.
template<int MASK>
__device__ __forceinline__ float xl(float v){
    int i = __builtin_bit_cast(int, v), r;
    if constexpr (MASK == 1)      r = __builtin_amdgcn_mov_dpp(i, 0xB1, 0xF, 0xF, true); // quad_perm [1,0,3,2]
    else if constexpr (MASK == 2) r = __builtin_amdgcn_mov_dpp(i, 0x4E, 0xF, 0xF, true); // quad_perm [2,3,0,1]
    else                          r = __builtin_amdgcn_ds_swizzle(i, (MASK << 10) | 0x1F); // BitMode xor
    return __builtin_bit_cast(float, r);
}
template<int MASK>
__device__ __forceinline__ C2 xl2(C2 v){ return { xl<MASK>(v.x), xl<MASK>(v.y) }; }

template<int MASK>
__device__ __forceinline__ C2 pair_op(C2 amp, C2 dg, C2 of){
    C2 p = xl2<MASK>(amp);
    return cadd(cmul(dg, amp), cmul(of, p));
}

// Apply gate from table entry c = {cb*cpg, cb*spg, sb*samg, sb*camg}.
// dg = { c.x, hi ? c.y : -c.y },  of = { hi ? -c.z : c.z, -c.w }.
template<int MASK>
__device__ __forceinline__ C2 gate_apply(C2 amp, float4 c, bool hi){
    const C2 dg = { c.x, hi ? c.y : -c.y };
    const C2 of = { hi ? -c.z : c.z, -c.w };
    return pair_op<MASK>(amp, dg, of);
}

__global__ __launch_bounds__(320)
void qp_kernel(const float* __restrict__ state,   // 16 f32
               const float* __restrict__ params,  // (3,4,2,5) = 120 f32
               const float* __restrict__ W,       // (2,9) f32
               const float* __restrict__ bias,    // (2,) f32
               float* __restrict__ out)           // (1,2) f32
{
    __shared__ float4 coef[40];   // per-gate coefficient table
    __shared__ float  r_lds[9];

    const int tid    = threadIdx.x;
    const int lane32 = tid & 31;   // amplitude index
    const int tstep  = tid >> 5;   // 0..8 valid, 9 = idle tail
    const int b0     = lane32 & 1;
    const float t    = 0.1f * (float)(tstep + 1);

    // Prefetch tail operands so their global latency hides under the chain.
    float wreg[9]; float breg = 0.f;
    if (tid < 2) {
        breg = bias[tid];
        #pragma unroll
        for (int q = 0; q < 9; ++q) wreg[q] = W[tid * 9 + q];
    }

    // ---- Phase 1: gate coefficient table (one gate per lane, wave 0) ----
    if (tid < 40) {
        const float a = params[tid], b = params[40 + tid], g = params[80 + tid];
        const float spg = __sinf(a + g), cpg = __cosf(a + g);
        const float sm  = __sinf(a - g), cm  = __cosf(a - g);
        const float sb  = __sinf(b),     cb  = __cosf(b);
        coef[tid] = make_float4(cb * cpg, cb * spg, sb * sm, sb * cm);
    }

    // psi = kron(state, [1,0])
    C2 amp = { b0 ? 0.f : state[lane32 >> 1], 0.f };

    // ---- H(t) 2x2 on pair (j, j^1): per-lane, layer-invariant ----
    const float fm  = (float)__popc(lane32 >> 1);
    const float hds = (b0 ? 1.f : -1.f) * (2.f * fm - 4.f);  // signed half-detuning
    const float Om  = sqrtf(hds * hds + 400.f);              // omega = -20
    const float sth = __sinf(Om * t), cth = __cosf(Om * t);
    const float k   = sth / Om;
    const float s4  = __sinf(4.f * t), c4 = __cosf(4.f * t);
    const C2 ph  = { c4, s4 };                               // e^{-ict}, c = -4
    const C2 hdg = cmul(ph, C2{ cth, -k * hds });
    const C2 hof = cmul(ph, C2{ 0.f, 20.f * k });            // -i k w, w = -20

    __syncthreads();

    const bool h16 = (lane32 & 16) != 0;
    const bool h8  = (lane32 &  8) != 0;
    const bool h4  = (lane32 &  4) != 0;
    const bool h2  = (lane32 &  2) != 0;
    const bool h1  = b0 != 0;

    #pragma unroll
    for (int l = 0; l < 4; ++l) {
        const int bA = l * 10, bB = bA + 5;
        amp = gate_apply<16>(amp, coef[bA + 0], h16);   // U1
        amp = gate_apply< 8>(amp, coef[bA + 1], h8);
        amp = gate_apply< 4>(amp, coef[bA + 2], h4);
        amp = gate_apply< 2>(amp, coef[bA + 3], h2);
        amp = gate_apply< 1>(amp, coef[bA + 4], h1);
        amp = pair_op<1>(amp, hdg, hof);                // H(t)
        amp = gate_apply<16>(amp, coef[bB + 0], h16);   // U2
        amp = gate_apply< 8>(amp, coef[bB + 1], h8);
        amp = gate_apply< 4>(amp, coef[bB + 2], h4);
        amp = gate_apply< 2>(amp, coef[bB + 3], h2);
        amp = gate_apply< 1>(amp, coef[bB + 4], h1);
    }

    // r[t] = sum_even |amp|^2 - sum_odd |amp|^2 within each 32-lane group
    const float p = amp.x * amp.x + amp.y * amp.y;
    float sp = b0 ? -p : p;
    sp += xl<16>(sp);
    sp += xl<8>(sp);
    sp += xl<4>(sp);
    sp += xl<2>(sp);
    sp += xl<1>(sp);
    if (lane32 == 0 && tstep < 9) r_lds[tstep] = sp;
    __syncthreads();

    // out[o] = tanh(sum_t r[t] * W[o,t] + bias[o])  -- W/bias already in regs
    if (tid < 2) {
        float acc = breg;
        #pragma unroll
        for (int q = 0; q < 9; ++q) acc += r_lds[q] * wreg[q];
        out[tid] = tanhf(acc);
    }
}

extern "C" void kernel_launch(void* const* d_in, const int* in_sizes, int n_in,
                              void* d_out, int out_size, void* d_ws, size_t ws_size,
                              hipStream_t stream) {
    const float* state  = (const float*)d_in[0];
    const float* params = (const float*)d_in[1];
    const float* W      = (const float*)d_in[2];
    const float* bias   = (const float*)d_in[3];
    float* out = (float*)d_out;
    qp_kernel<<<1, 320, 0, stream>>>(state, params, W, bias, out);
}

// Round 6
// 9.611 us; speedup vs baseline: 1.3121x; 1.0119x over previous
//
#include <hip/hip_runtime.h>
#include <math.h>

// QuantumPerceptron: 5 qubits (DIM=32), 4 layers, 9 time steps.
// R6 = R5 structure with ONLY session-proven exchange primitives (R5's
// permlane16/32_swap builtins are the prime suspect for its failure).
// Layout: amp bit0 in registers (2 complex amps/lane; H and qubit-4 gate are
// register 2x2s). amp bits 1,2 <- lane bits 0,1 (quad_perm DPP). amp bits
// 3,4 <- lane bits 2,3 (ds_swizzle masks 4,8 — proven in R2-R4). Time <- lane
// bits 4,5 (+ wave*4): 3 waves of 4 time slots, 9 of 12 used. Gate
// coefficients (time/lane-invariant) in LDS, built once by lanes 0..39.

struct C2 { float x, y; };
__device__ __forceinline__ C2 cmul(C2 a, C2 b){ return {a.x*b.x - a.y*b.y, a.x*b.y + a.y*b.x}; }
__device__ __forceinline__ C2 cadd(C2 a, C2 b){ return {a.x+b.x, a.y+b.y}; }

template<int PAT>
__device__ __forceinline__ float qperm(float v){
    int r = __builtin_amdgcn_mov_dpp(__builtin_bit_cast(int, v), PAT, 0xF, 0xF, true);
    return __builtin_bit_cast(float, r);
}
template<int MASK>
__device__ __forceinline__ float swz(float v){
    int r = __builtin_amdgcn_ds_swizzle(__builtin_bit_cast(int, v), (MASK << 10) | 0x1F);
    return __builtin_bit_cast(float, r);
}

// Gate on amp bit0 (register pair). c = {cb*cpg, cb*spg, sb*samg, sb*camg}.
// G00={c.x,-c.y} G01={c.z,-c.w} G10={-c.z,-c.w} G11={c.x,c.y}
__device__ __forceinline__ void gate_reg(C2& a0, C2& a1, float4 c){
    const C2 n0 = { c.x*a0.x + c.y*a0.y + c.z*a1.x + c.w*a1.y,
                    c.x*a0.y - c.y*a0.x + c.z*a1.y - c.w*a1.x };
    const C2 n1 = { -c.z*a0.x + c.w*a0.y + c.x*a1.x - c.y*a1.y,
                    -c.z*a0.y - c.w*a0.x + c.x*a1.y + c.y*a1.x };
    a0 = n0; a1 = n1;
}

// Gate on lane-resident amp bit, partner via quad_perm DPP (lane bits 0,1).
// dg={c.x,s1}, of={s2,-c.w}; s1 = hi? c.y:-c.y, s2 = hi? -c.z:c.z.  (R4-proven)
template<int PAT>
__device__ __forceinline__ void gate_q(C2& a0, C2& a1, float4 c, bool hi){
    const float s1 = hi ? c.y : -c.y;
    const float s2 = hi ? -c.z : c.z;
    const C2 p0 = { qperm<PAT>(a0.x), qperm<PAT>(a0.y) };
    const C2 p1 = { qperm<PAT>(a1.x), qperm<PAT>(a1.y) };
    a0 = { c.x*a0.x - s1*a0.y + s2*p0.x + c.w*p0.y,
           c.x*a0.y + s1*a0.x + s2*p0.y - c.w*p0.x };
    a1 = { c.x*a1.x - s1*a1.y + s2*p1.x + c.w*p1.y,
           c.x*a1.y + s1*a1.x + s2*p1.y - c.w*p1.x };
}

// Same gate, partner via ds_swizzle (lane bits 2,3 -> masks 4,8).  (R2/R4-proven)
template<int MASK>
__device__ __forceinline__ void gate_sw(C2& a0, C2& a1, float4 c, bool hi){
    const float s1 = hi ? c.y : -c.y;
    const float s2 = hi ? -c.z : c.z;
    const C2 p0 = { swz<MASK>(a0.x), swz<MASK>(a0.y) };
    const C2 p1 = { swz<MASK>(a1.x), swz<MASK>(a1.y) };
    a0 = { c.x*a0.x - s1*a0.y + s2*p0.x + c.w*p0.y,
           c.x*a0.y + s1*a0.x + s2*p0.y - c.w*p0.x };
    a1 = { c.x*a1.x - s1*a1.y + s2*p1.x + c.w*p1.y,
           c.x*a1.y + s1*a1.x + s2*p1.y - c.w*p1.x };
}

__global__ __launch_bounds__(192)
void qp_kernel(const float* __restrict__ state,   // 16 f32
               const float* __restrict__ params,  // (3,4,2,5) = 120 f32
               const float* __restrict__ W,       // (2,9) f32
               const float* __restrict__ bias,    // (2,) f32
               float* __restrict__ out)           // (1,2) f32
{
    __shared__ float4 coef[40];
    __shared__ float  r_lds[9];

    const int tid  = threadIdx.x;
    const int lane = tid & 63;
    const int wv   = tid >> 6;

    // Prefetch tail operands so their global latency hides under the chain.
    float wreg[9]; float breg = 0.f;
    if (tid < 2) {
        breg = bias[tid];
        #pragma unroll
        for (int q = 0; q < 9; ++q) wreg[q] = W[tid * 9 + q];
    }

    // Phase 1: gate coefficient table (one gate per lane, wave 0).
    if (tid < 40) {
        const float a = params[tid], b = params[40 + tid], g = params[80 + tid];
        const float spg = __sinf(a + g), cpg = __cosf(a + g);
        const float sm  = __sinf(a - g), cm  = __cosf(a - g);
        const float sb  = __sinf(b),     cb  = __cosf(b);
        coef[tid] = make_float4(cb * cpg, cb * spg, sb * sm, sb * cm);
    }

    // amp bits 1..4 <- lane bits 0..3 ; time <- lane bits 4,5 (+ wave*4)
    const int idx  = lane & 0xF;                 // amp index >> 1
    const int t_i  = (lane >> 4) + wv * 4;       // 0..11, valid < 9
    const float tv = 0.1f * (float)(t_i + 1);

    // psi = kron(state,[1,0]): a0 (amp bit0=0) = state[idx], a1 = 0
    C2 a0 = { state[idx], 0.f }, a1 = { 0.f, 0.f };

    const bool h1 = (lane & 1) != 0;   // amp bit1 (qubit3)
    const bool h2 = (lane & 2) != 0;   // amp bit2 (qubit2)
    const bool h3 = (lane & 4) != 0;   // amp bit3 (qubit1)
    const bool h4 = (lane & 8) != 0;   // amp bit4 (qubit0)

    // H(t) on the register pair (layer-invariant, uniform per lane)
    const float fm = (float)__popc(idx);
    const float hd = 2.f * fm - 4.f;
    const float Om = sqrtf(hd * hd + 400.f);              // omega = -20
    const float sth = __sinf(Om * tv), cth = __cosf(Om * tv);
    const float k  = sth / Om;
    const float s4 = __sinf(4.f * tv), c4 = __cosf(4.f * tv);
    const C2 ph  = { c4, s4 };                            // e^{-ict}, c = -4
    const C2 dgE = cmul(ph, C2{ cth,  k * hd });          // slot a0 (b0=0)
    const C2 dgO = cmul(ph, C2{ cth, -k * hd });          // slot a1 (b0=1)
    const C2 hof = cmul(ph, C2{ 0.f, 20.f * k });

    __syncthreads();

    #pragma unroll
    for (int l = 0; l < 4; ++l) {
        const int bA = l * 10, bB = bA + 5;
        gate_sw<8>(a0, a1, coef[bA + 0], h4);     // qubit0 -> amp bit4 (lane bit3)
        gate_sw<4>(a0, a1, coef[bA + 1], h3);     // qubit1 -> amp bit3 (lane bit2)
        gate_q<0x4E>(a0, a1, coef[bA + 2], h2);   // qubit2 -> amp bit2 (lane bit1)
        gate_q<0xB1>(a0, a1, coef[bA + 3], h1);   // qubit3 -> amp bit1 (lane bit0)
        gate_reg(a0, a1, coef[bA + 4]);           // qubit4 -> amp bit0 (register)
        {   // H(t): register 2x2
            const C2 n0 = cadd(cmul(dgE, a0), cmul(hof, a1));
            const C2 n1 = cadd(cmul(hof, a0), cmul(dgO, a1));
            a0 = n0; a1 = n1;
        }
        gate_sw<8>(a0, a1, coef[bB + 0], h4);
        gate_sw<4>(a0, a1, coef[bB + 1], h3);
        gate_q<0x4E>(a0, a1, coef[bB + 2], h2);
        gate_q<0xB1>(a0, a1, coef[bB + 3], h1);
        gate_reg(a0, a1, coef[bB + 4]);
    }

    // r[t] = sum_even |amp|^2 - sum_odd |amp|^2 (even = slot a0)
    float pr = a0.x*a0.x + a0.y*a0.y - a1.x*a1.x - a1.y*a1.y;
    pr += qperm<0xB1>(pr);   // amp bit1
    pr += qperm<0x4E>(pr);   // amp bit2
    pr += swz<4>(pr);        // amp bit3
    pr += swz<8>(pr);        // amp bit4
    if ((lane & 0xF) == 0 && t_i < 9) r_lds[t_i] = pr;
    __syncthreads();

    // out[o] = tanh(sum_t r[t]*W[o,t] + bias[o])
    if (tid < 2) {
        float acc = breg;
        #pragma unroll
        for (int q = 0; q < 9; ++q) acc += r_lds[q] * wreg[q];
        out[tid] = tanhf(acc);
    }
}

extern "C" void kernel_launch(void* const* d_in, const int* in_sizes, int n_in,
                              void* d_out, int out_size, void* d_ws, size_t ws_size,
                              hipStream_t stream) {
    const float* state  = (const float*)d_in[0];
    const float* params = (const float*)d_in[1];
    const float* W      = (const float*)d_in[2];
    const float* bias   = (const float*)d_in[3];
    float* out = (float*)d_out;
    qp_kernel<<<1, 192, 0, stream>>>(state, params, W, bias, out);
}